// Round 4
// baseline (411.730 us; speedup 1.0000x reference)
//
#include <hip/hip_runtime.h>

#define NN 400
#define FF 240
#define CC 32
#define NIN 304   // F + 2C
#define LL 1440
#define KSPLIT 8
#define KCHUNK 50     // NN / KSPLIT
#define NTILE 13      // ceil(400/32)

struct Params {
    const float *x, *a, *e0;
    const float *c1_sw, *c1_sb, *c1_aiw, *c1_aib, *c1_ajw, *c1_ajb;
    const float *c1_nw, *c1_nb, *c1_ew, *c1_eb;
    const float *c2_sw, *c2_sb, *c2_aiw, *c2_aib, *c2_ajw, *c2_ajb;
    const float *c2_nw, *c2_nb;
    const float *dw, *db;
    float *out;
    float *P, *Q, *aggiP, *aggjP, *x1, *e1;   // ws regions (x2 aliases e1)
    float *aT, *eT;                            // aliased into out (dead until dense)
    unsigned *bar;                             // barrier state in ws (memset 0 per call)
};

// ---------------- grid-wide barrier (all blocks co-resident by construction) ----
__device__ __forceinline__ void grid_barrier(unsigned* bar, int phase) {
    __syncthreads();
    __threadfence();                       // release prior writes (agent scope)
    if (threadIdx.x == 0) {
        unsigned* gcount = bar;            // 64 groups * 16 dwords
        unsigned* grel   = bar + 1024;
        unsigned* master = bar + 2048;
        const unsigned g       = blockIdx.x >> 5;
        const unsigned ngroups = (gridDim.x + 31) >> 5;
        const unsigned gsz     = min(32u, gridDim.x - (g << 5));
        unsigned* cnt = gcount + g * 16;
        unsigned* rel = grel + g * 16;
        const unsigned r = atomicAdd(cnt, 1u);
        if (r + 1u == (unsigned)phase * gsz) {           // group finisher
            atomicAdd(master, 1u);
            while (__hip_atomic_load(master, __ATOMIC_RELAXED, __HIP_MEMORY_SCOPE_AGENT)
                   < (unsigned)phase * ngroups)
                __builtin_amdgcn_s_sleep(2);
            __hip_atomic_store(rel, (unsigned)phase, __ATOMIC_RELAXED, __HIP_MEMORY_SCOPE_AGENT);
        } else {
            while (__hip_atomic_load(rel, __ATOMIC_RELAXED, __HIP_MEMORY_SCOPE_AGENT)
                   < (unsigned)phase)
                __builtin_amdgcn_s_sleep(2);
        }
    }
    __syncthreads();
    __threadfence();                       // acquire
}

// ---------------- phase bodies -------------------------------------------------
__device__ __forceinline__ void transpose_job(const float* __restrict__ src,
                                              float* __restrict__ dst,
                                              int job, int t, float* smem) {
    const int tr = job / NTILE, tc = job % NTILE;
    const int lc = t & 31, lr0 = t >> 5;
    #pragma unroll
    for (int pp = 0; pp < 4; ++pp) {
        const int r = tr * 32 + lr0 + pp * 8, c = tc * 32 + lc;
        smem[(lr0 + pp * 8) * 33 + lc] = (r < NN && c < NN) ? src[r * NN + c] : 0.0f;
    }
    __syncthreads();
    #pragma unroll
    for (int pp = 0; pp < 4; ++pp) {
        const int r2 = tc * 32 + lr0 + pp * 8, c2 = tr * 32 + lc;
        if (r2 < NN && c2 < NN) dst[r2 * NN + c2] = smem[lc * 33 + (lr0 + pp * 8)];
    }
    __syncthreads();
}

__device__ __forceinline__ void pq_job(const float* __restrict__ x,
                                       const float* __restrict__ sw,
                                       const float* __restrict__ sb,
                                       float* __restrict__ P, float* __restrict__ Q,
                                       int i, int t, float* smem) {
    const int c = t & 31, isQ = (t >> 5) & 1, g = t >> 6;   // 4 f-quarters of 60
    const float* wb = sw + (isQ ? FF * CC : 0) + c;
    float acc = (!isQ && g == 0) ? sb[c] : 0.0f;
    const float* xr = x + i * FF;
    const int f0 = g * 60;
    #pragma unroll 4
    for (int f = f0; f < f0 + 60; ++f) acc += xr[f] * wb[f * CC];
    smem[g * 64 + (t & 63)] = acc;
    __syncthreads();
    if (t < 64) {
        const float s = smem[t] + smem[64 + t] + smem[128 + t] + smem[192 + t];
        if (t >= 32) Q[i * CC + (t & 31)] = s;
        else         P[i * CC + t] = s;
    }
    __syncthreads();
}

template<bool WRITE_E>
__device__ __forceinline__ void rcf_phase(const Params& p,
        const float* __restrict__ e, const float* __restrict__ eT,
        const float* __restrict__ sw,
        const float* __restrict__ aiw, const float* __restrict__ aib,
        const float* __restrict__ ajw, const float* __restrict__ ajb,
        const float* __restrict__ ew, const float* __restrict__ eb,
        float* __restrict__ e_out, float* smem) {
    const int t = threadIdx.x;
    const int pg = t >> 3, l = t & 7, c0 = l * 4;
    const float* swt = sw + 480 * CC;
    float w1v[4], w2v[4], wiv[4], wjv[4], wev[4];
    *(float4*)w1v = *(const float4*)(swt + c0);
    *(float4*)w2v = *(const float4*)(swt + CC + c0);
    *(float4*)wiv = *(const float4*)(aiw + c0);
    *(float4*)wjv = *(const float4*)(ajw + c0);
    if (WRITE_E) *(float4*)wev = *(const float4*)(ew + c0);
    const float bi = aib[0], bj = ajb[0];
    const float be = WRITE_E ? eb[0] : 0.0f;

    for (int job = blockIdx.x; job < NN * KSPLIT; job += gridDim.x) {
        const int b = job >> 3, kb = job & 7;
        float Pb[4], Qb[4];
        *(float4*)Pb = *(const float4*)(p.P + b * CC + c0);
        *(float4*)Qb = *(const float4*)(p.Q + b * CC + c0);
        float acc_i[4] = {0, 0, 0, 0}, acc_j[4] = {0, 0, 0, 0};
        const int kbase = kb * KCHUNK;
        #pragma unroll
        for (int it = 0; it < 2; ++it) {
            const int off = it * 32 + pg;
            const bool valid = off < KCHUNK;
            const int k = kbase + (valid ? off : 0);
            float Qk[4], Pk[4];
            *(float4*)Qk = *(const float4*)(p.Q + k * CC + c0);
            *(float4*)Pk = *(const float4*)(p.P + k * CC + c0);
            const float e_f  = e[b * NN + k];          // row: coalesced
            const float e_r  = eT[b * NN + k];         // transposed copy: coalesced
            const float a_bk = p.a[b * NN + k];
            const float a_kb = p.aT[b * NN + k];
            float sr[4], sc[4];
            #pragma unroll
            for (int q = 0; q < 4; ++q) {
                sr[q] = fmaxf(Pb[q] + Qk[q] + e_f * w1v[q] + e_r * w2v[q], 0.0f) * a_bk;
                sc[q] = fmaxf(Pk[q] + Qb[q] + e_r * w1v[q] + e_f * w2v[q], 0.0f) * a_kb;
            }
            float d_i = sr[0] * wiv[0] + sr[1] * wiv[1] + sr[2] * wiv[2] + sr[3] * wiv[3];
            float d_j = sc[0] * wjv[0] + sc[1] * wjv[1] + sc[2] * wjv[2] + sc[3] * wjv[3];
            float d_e = WRITE_E ? (sr[0] * wev[0] + sr[1] * wev[1] + sr[2] * wev[2] + sr[3] * wev[3]) : 0.0f;
            #pragma unroll
            for (int m = 1; m < 8; m <<= 1) {
                d_i += __shfl_xor(d_i, m);
                d_j += __shfl_xor(d_j, m);
                if (WRITE_E) d_e += __shfl_xor(d_e, m);
            }
            const float gi = valid ? 1.0f / (1.0f + __expf(-(d_i + bi))) : 0.0f;
            const float gj = valid ? 1.0f / (1.0f + __expf(-(d_j + bj))) : 0.0f;
            #pragma unroll
            for (int q = 0; q < 4; ++q) {
                acc_i[q] += gi * sr[q];
                acc_j[q] += gj * sc[q];
            }
            if (WRITE_E && l == 0 && valid) e_out[b * NN + k] = d_e + be;
        }
        #pragma unroll
        for (int q = 0; q < 4; ++q) {
            smem[(pg) * 36 + c0 + q]        = acc_i[q];
            smem[(32 + pg) * 36 + c0 + q]   = acc_j[q];
        }
        __syncthreads();
        if (t < 64) {
            const int which = t >> 5, c = t & 31;
            float s = 0.0f;
            #pragma unroll
            for (int g2 = 0; g2 < 32; ++g2) s += smem[(which * 32 + g2) * 36 + c];
            float* dst = which ? p.aggjP : p.aggiP;
            dst[kb * NN * CC + b * CC + c] = s;
        }
        __syncthreads();
    }
}

template<bool DO_PQ>
__device__ __forceinline__ void npq_job(const float* __restrict__ xin,
        const float* __restrict__ aggiP, const float* __restrict__ aggjP,
        const float* __restrict__ nw, const float* __restrict__ nb,
        const float* __restrict__ sw, const float* __restrict__ sb,
        float* __restrict__ xout, float* __restrict__ Pout, float* __restrict__ Qout,
        int i, int t, float* smem) {
    float* v    = smem;         // 304
    float* xs   = smem + 304;   // 240
    float* red2 = smem + 544;   // 256
    if (t < FF) v[t] = xin[i * FF + t];
    if (t < 64) {
        const float* base = (t < CC) ? (aggiP + i * CC + t) : (aggjP + i * CC + (t - CC));
        float s = 0.0f;
        #pragma unroll
        for (int pp = 0; pp < KSPLIT; ++pp) s += base[pp * NN * CC];
        v[FF + t] = s;
    }
    __syncthreads();
    if (t < FF) {
        float acc = nb[t];
        #pragma unroll 4
        for (int k = 0; k < NIN; ++k) acc += v[k] * nw[k * FF + t];
        xout[i * FF + t] = acc;
        xs[t] = acc;
    }
    __syncthreads();
    if (DO_PQ) {
        const int c = t & 31, isQ = (t >> 5) & 1, g = t >> 6;
        const float* wb = sw + (isQ ? FF * CC : 0) + c;
        float acc = (!isQ && g == 0) ? sb[c] : 0.0f;
        const int f0 = g * 60;
        #pragma unroll 4
        for (int f = f0; f < f0 + 60; ++f) acc += xs[f] * wb[f * CC];
        red2[g * 64 + (t & 63)] = acc;
        __syncthreads();
        if (t < 64) {
            const float s = red2[t] + red2[64 + t] + red2[128 + t] + red2[192 + t];
            if (t >= 32) Qout[i * CC + (t & 31)] = s;
            else         Pout[i * CC + t] = s;
        }
        __syncthreads();
    }
}

__device__ __forceinline__ void dense_job(const float* __restrict__ x2,
        const float* __restrict__ dw, const float* __restrict__ db,
        float* __restrict__ out, int job, int t, float* smem) {
    const int i0 = (job / 6) * 4;
    const int lb = job % 6;
    for (int idx = t; idx < 4 * FF; idx += 256) {
        const int r = idx / FF, f = idx - r * FF;
        smem[r * FF + f] = x2[(i0 + r) * FF + f];
    }
    __syncthreads();
    const int l1 = lb * 256 + t;
    if (l1 < LL) {
        float a0 = db[l1], a1 = a0, a2 = a0, a3 = a0;
        #pragma unroll 4
        for (int f = 0; f < FF; ++f) {
            const float w = dw[f * LL + l1];
            a0 += smem[f] * w;
            a1 += smem[FF + f] * w;
            a2 += smem[2 * FF + f] * w;
            a3 += smem[3 * FF + f] * w;
        }
        out[(i0 + 0) * LL + l1] = a0;
        out[(i0 + 1) * LL + l1] = a1;
        out[(i0 + 2) * LL + l1] = a2;
        out[(i0 + 3) * LL + l1] = a3;
    }
    __syncthreads();
}

// ---------------- the mono kernel ---------------------------------------------
__global__ __launch_bounds__(256) void xenet_mono(Params p) {
    __shared__ float smem[2560];
    const int t = threadIdx.x;

    // P0: pq layer1 + transpose a, e0 (transposes live in d_out's dead space)
    for (int job = blockIdx.x; job < 400 + 169 + 169; job += gridDim.x) {
        if (job < 400)      pq_job(p.x, p.c1_sw, p.c1_sb, p.P, p.Q, job, t, smem);
        else if (job < 569) transpose_job(p.a, p.aT, job - 400, t, smem);
        else                transpose_job(p.e0, p.eT, job - 569, t, smem);
    }
    grid_barrier(p.bar, 1);

    // P1: rcf layer1 (writes agg partials + e1)
    rcf_phase<true>(p, p.e0, p.eT, p.c1_sw, p.c1_aiw, p.c1_aib, p.c1_ajw, p.c1_ajb,
                    p.c1_ew, p.c1_eb, p.e1, smem);
    grid_barrier(p.bar, 2);

    // P2: node layer1 + PQ layer2, and transpose e1 -> eT (e0T dead now)
    for (int job = blockIdx.x; job < 400 + 169; job += gridDim.x) {
        if (job < 400)
            npq_job<true>(p.x, p.aggiP, p.aggjP, p.c1_nw, p.c1_nb, p.c2_sw, p.c2_sb,
                          p.x1, p.P, p.Q, job, t, smem);
        else
            transpose_job(p.e1, p.eT, job - 400, t, smem);
    }
    grid_barrier(p.bar, 3);

    // P3: rcf layer2 (no e_out)
    rcf_phase<false>(p, p.e1, p.eT, p.c2_sw, p.c2_aiw, p.c2_aib, p.c2_ajw, p.c2_ajb,
                     nullptr, nullptr, nullptr, smem);
    grid_barrier(p.bar, 4);

    // P4: node layer2 -> x2 (aliases e1, dead after P3)
    for (int job = blockIdx.x; job < 400; job += gridDim.x)
        npq_job<false>(p.x1, p.aggiP, p.aggjP, p.c2_nw, p.c2_nb, nullptr, nullptr,
                       p.e1, nullptr, nullptr, job, t, smem);
    grid_barrier(p.bar, 5);

    // P5: final dense (overwrites out, incl. the aT/eT scratch regions)
    for (int job = blockIdx.x; job < 600; job += gridDim.x)
        dense_job(p.e1, p.dw, p.db, p.out, job, t, smem);
}

extern "C" void kernel_launch(void* const* d_in, const int* in_sizes, int n_in,
                              void* d_out, int out_size, void* d_ws, size_t ws_size,
                              hipStream_t stream) {
    Params p;
    p.x  = (const float*)d_in[0];
    p.a  = (const float*)d_in[1];
    p.e0 = (const float*)d_in[2];
    p.c1_sw  = (const float*)d_in[3];
    p.c1_sb  = (const float*)d_in[4];
    p.c1_aiw = (const float*)d_in[5];
    p.c1_aib = (const float*)d_in[6];
    p.c1_ajw = (const float*)d_in[7];
    p.c1_ajb = (const float*)d_in[8];
    p.c1_nw  = (const float*)d_in[9];
    p.c1_nb  = (const float*)d_in[10];
    p.c1_ew  = (const float*)d_in[11];
    p.c1_eb  = (const float*)d_in[12];
    p.c2_sw  = (const float*)d_in[13];
    p.c2_sb  = (const float*)d_in[14];
    p.c2_aiw = (const float*)d_in[15];
    p.c2_aib = (const float*)d_in[16];
    p.c2_ajw = (const float*)d_in[17];
    p.c2_ajb = (const float*)d_in[18];
    p.c2_nw  = (const float*)d_in[19];
    p.c2_nb  = (const float*)d_in[20];
    // d_in[21] = c2_ew, d_in[22] = c2_eb: layer-2 edge output is dead code
    p.dw = (const float*)d_in[23];
    p.db = (const float*)d_in[24];
    p.out = (float*)d_out;

    float* ws = (float*)d_ws;
    p.P     = ws;                    // 12800
    p.Q     = ws + 12800;            // 12800
    p.aggiP = ws + 25600;            // 102400
    p.aggjP = ws + 128000;           // 102400
    p.x1    = ws + 230400;           // 96000
    p.e1    = ws + 326400;           // 160000 (x2 aliases this after P3)
    p.aT    = (float*)d_out;         // 160000 (out is 576000; overwritten in P5)
    p.eT    = (float*)d_out + 160000;// 160000
    p.bar   = (unsigned*)(ws + 487424);  // 2064+ dwords, < proven ws size

    // reset barrier state every call (capture-safe memset node)
    hipMemsetAsync((void*)p.bar, 0, 2080 * sizeof(unsigned), stream);

    int occ = 0;
    if (hipOccupancyMaxActiveBlocksPerMultiprocessor(&occ, xenet_mono, 256, 0) != hipSuccess || occ < 1)
        occ = 2;
    int grid = occ * 256;            // 256 CUs on MI355X; all blocks co-resident
    if (grid > 2048) grid = 2048;

    xenet_mono<<<grid, 256, 0, stream>>>(p);
}

// Round 6
// 72.666 us; speedup vs baseline: 5.6660x; 5.6660x over previous
//
#include <hip/hip_runtime.h>

#define NN 400
#define FF 240
#define CC 32
#define NIN 304   // F + 2C
#define LL 1440
#define NITER 13  // ceil(400/32)

// ---------------------------------------------------------------------------
// K1: P[i][c] = sb[c] + sum_f x[i][f]*sw[f*C+c] ; Q likewise with sw[F:2F].
// grid = N blocks, 256 threads.
// ---------------------------------------------------------------------------
__global__ __launch_bounds__(256) void pq_kernel(
    const float* __restrict__ x, const float* __restrict__ sw,
    const float* __restrict__ sb, float* __restrict__ P, float* __restrict__ Q) {
    const int i   = blockIdx.x;
    const int t   = threadIdx.x;
    const int c   = t & 31;
    const int isQ = (t >> 5) & 1;
    const int g   = t >> 6;            // 0..3, 60 f each
    const float* wb = sw + (isQ ? FF * CC : 0) + c;
    float acc = (!isQ && g == 0) ? sb[c] : 0.0f;
    const float* xr = x + i * FF;
    const int f0 = g * 60;
    #pragma unroll 4
    for (int f = f0; f < f0 + 60; ++f) acc += xr[f] * wb[f * CC];
    __shared__ float red[4][64];
    red[g][t & 63] = acc;
    __syncthreads();
    if (t < 64) {
        const float s = red[0][t] + red[1][t] + red[2][t] + red[3][t];
        if (t >= 32) Q[i * CC + (t & 31)] = s;
        else         P[i * CC + t] = s;
    }
}

// ---------------------------------------------------------------------------
// K2/K3: one block per row b. rcf (row+col gates over ALL 400 k) with agg
// reduced entirely in LDS, then the node model for row b inline, then
// (layer 1 only) the next layer's P/Q projection. No cross-block traffic.
// 256 threads: pg = t>>3 pair-group (32 pairs/iter), l = t&7 channel quad.
// ---------------------------------------------------------------------------
template<bool WRITE_E, bool DO_PQ>
__global__ __launch_bounds__(256) void rcf_node(
    const float* __restrict__ P, const float* __restrict__ Q,
    const float* __restrict__ e, const float* __restrict__ a,
    const float* __restrict__ sw_tail,   // sw + 480*CC : rows [w1 ; w2]
    const float* __restrict__ aiw, const float* __restrict__ aib,
    const float* __restrict__ ajw, const float* __restrict__ ajb,
    const float* __restrict__ ew, const float* __restrict__ eb,
    float* __restrict__ e_out,
    const float* __restrict__ xin, const float* __restrict__ nw,
    const float* __restrict__ nb,
    const float* __restrict__ sw2, const float* __restrict__ sb2,
    float* __restrict__ xout, float* __restrict__ Pout, float* __restrict__ Qout) {
    const int b  = blockIdx.x;
    const int t  = threadIdx.x;
    const int pg = t >> 3, l = t & 7, c0 = l * 4;

    __shared__ float smem[4064];
    float* red  = smem;          // 2304 = 64*36 (rcf reduction)
    float* v    = smem + 2304;   // 304 (node input vector)
    float* xs   = smem + 2608;   // 240 (node output row)
    float* redn = smem + 2848;   // 960 = 4*240
    float* red2 = smem + 3808;   // 256 = 4*64

    if (t < FF) v[t] = xin[b * FF + t];   // stage x-row early (hidden under rcf)

    // ---- rcf: both gate directions for row b over all k ----
    float w1v[4], w2v[4], wiv[4], wjv[4], wev[4], Pb[4], Qb[4];
    *(float4*)w1v = *(const float4*)(sw_tail + c0);
    *(float4*)w2v = *(const float4*)(sw_tail + CC + c0);
    *(float4*)wiv = *(const float4*)(aiw + c0);
    *(float4*)wjv = *(const float4*)(ajw + c0);
    if (WRITE_E) *(float4*)wev = *(const float4*)(ew + c0);
    *(float4*)Pb = *(const float4*)(P + b * CC + c0);
    *(float4*)Qb = *(const float4*)(Q + b * CC + c0);
    const float bi = aib[0], bj = ajb[0];
    const float be = WRITE_E ? eb[0] : 0.0f;

    float acc_i[4] = {0, 0, 0, 0}, acc_j[4] = {0, 0, 0, 0};
    #pragma unroll 4
    for (int it = 0; it < NITER; ++it) {
        const int off = it * 32 + pg;
        const bool valid = off < NN;
        const int k = valid ? off : 0;
        float Qk[4], Pk[4];
        *(float4*)Qk = *(const float4*)(Q + k * CC + c0);
        *(float4*)Pk = *(const float4*)(P + k * CC + c0);
        const float e_f  = e[b * NN + k];
        const float e_r  = e[k * NN + b];
        const float a_bk = a[b * NN + k];
        const float a_kb = a[k * NN + b];
        float sr[4], sc[4];
        #pragma unroll
        for (int q = 0; q < 4; ++q) {
            sr[q] = fmaxf(Pb[q] + Qk[q] + e_f * w1v[q] + e_r * w2v[q], 0.0f) * a_bk;
            sc[q] = fmaxf(Pk[q] + Qb[q] + e_r * w1v[q] + e_f * w2v[q], 0.0f) * a_kb;
        }
        float d_i = sr[0] * wiv[0] + sr[1] * wiv[1] + sr[2] * wiv[2] + sr[3] * wiv[3];
        float d_j = sc[0] * wjv[0] + sc[1] * wjv[1] + sc[2] * wjv[2] + sc[3] * wjv[3];
        float d_e = WRITE_E ? (sr[0] * wev[0] + sr[1] * wev[1] + sr[2] * wev[2] + sr[3] * wev[3]) : 0.0f;
        #pragma unroll
        for (int m = 1; m < 8; m <<= 1) {
            d_i += __shfl_xor(d_i, m);
            d_j += __shfl_xor(d_j, m);
            if (WRITE_E) d_e += __shfl_xor(d_e, m);
        }
        const float gi = valid ? 1.0f / (1.0f + __expf(-(d_i + bi))) : 0.0f;
        const float gj = valid ? 1.0f / (1.0f + __expf(-(d_j + bj))) : 0.0f;
        #pragma unroll
        for (int q = 0; q < 4; ++q) {
            acc_i[q] += gi * sr[q];
            acc_j[q] += gj * sc[q];
        }
        if (WRITE_E && l == 0 && valid) e_out[b * NN + k] = d_e + be;
    }
    #pragma unroll
    for (int q = 0; q < 4; ++q) {
        red[pg * 36 + c0 + q]        = acc_i[q];
        red[(32 + pg) * 36 + c0 + q] = acc_j[q];
    }
    __syncthreads();
    if (t < 64) {   // agg_i (t<32) / agg_j (t>=32) land directly in v[240+t]
        const int which = t >> 5, c = t & 31;
        float s = 0.0f;
        #pragma unroll
        for (int g2 = 0; g2 < 32; ++g2) s += red[(which * 32 + g2) * 36 + c];
        v[FF + t] = s;
    }
    __syncthreads();

    // ---- node model: xout[b] = nb + v @ nw  (304 x 240) ----
    {
        const int fg = t % 60, h = t / 60;   // t<240 active, 4 k-chunks of 76
        if (t < 240) {
            const int f0 = fg * 4;
            float4 acc = make_float4(0.f, 0.f, 0.f, 0.f);
            const int k0 = h * 76;
            #pragma unroll 4
            for (int k = k0; k < k0 + 76; ++k) {
                const float vk = v[k];
                const float4 w = *(const float4*)(nw + k * FF + f0);
                acc.x += vk * w.x; acc.y += vk * w.y;
                acc.z += vk * w.z; acc.w += vk * w.w;
            }
            *(float4*)(redn + h * 240 + f0) = acc;
        }
    }
    __syncthreads();
    if (t < FF) {
        const float r = nb[t] + redn[t] + redn[240 + t] + redn[480 + t] + redn[720 + t];
        xout[b * FF + t] = r;
        xs[t] = r;
    }
    if (DO_PQ) {
        __syncthreads();
        const int c = t & 31, isQ = (t >> 5) & 1, g = t >> 6;
        const float* wb = sw2 + (isQ ? FF * CC : 0) + c;
        float acc = (!isQ && g == 0) ? sb2[c] : 0.0f;
        const int f0 = g * 60;
        #pragma unroll 4
        for (int f = f0; f < f0 + 60; ++f) acc += xs[f] * wb[f * CC];
        red2[g * 64 + (t & 63)] = acc;
        __syncthreads();
        if (t < 64) {
            const float s = red2[t] + red2[64 + t] + red2[128 + t] + red2[192 + t];
            if (t >= 32) Qout[b * CC + (t & 31)] = s;
            else         Pout[b * CC + t] = s;
        }
    }
}

// ---------------------------------------------------------------------------
// K4: out[i][l] = db[l] + sum_f x2[i][f]*dw[f*L+l], 4 rows/block for dw reuse
// grid = (N/4, 6) blocks, 256 threads
// ---------------------------------------------------------------------------
__global__ __launch_bounds__(256) void dense_kernel(
    const float* __restrict__ x, const float* __restrict__ dw,
    const float* __restrict__ db, float* __restrict__ out) {
    const int i0 = blockIdx.x * 4;
    const int l  = blockIdx.y * 256 + threadIdx.x;
    __shared__ float xs[4][FF];
    for (int idx = threadIdx.x; idx < 4 * FF; idx += 256) {
        const int r = idx / FF, f = idx - r * FF;
        xs[r][f] = x[(i0 + r) * FF + f];
    }
    __syncthreads();
    if (l < LL) {
        float a0 = db[l], a1 = a0, a2 = a0, a3 = a0;
        #pragma unroll 4
        for (int f = 0; f < FF; ++f) {
            const float w = dw[f * LL + l];
            a0 += xs[0][f] * w;
            a1 += xs[1][f] * w;
            a2 += xs[2][f] * w;
            a3 += xs[3][f] * w;
        }
        out[(i0 + 0) * LL + l] = a0;
        out[(i0 + 1) * LL + l] = a1;
        out[(i0 + 2) * LL + l] = a2;
        out[(i0 + 3) * LL + l] = a3;
    }
}

extern "C" void kernel_launch(void* const* d_in, const int* in_sizes, int n_in,
                              void* d_out, int out_size, void* d_ws, size_t ws_size,
                              hipStream_t stream) {
    const float* x  = (const float*)d_in[0];
    const float* a  = (const float*)d_in[1];
    const float* e0 = (const float*)d_in[2];

    const float* c1_sw  = (const float*)d_in[3];
    const float* c1_sb  = (const float*)d_in[4];
    const float* c1_aiw = (const float*)d_in[5];
    const float* c1_aib = (const float*)d_in[6];
    const float* c1_ajw = (const float*)d_in[7];
    const float* c1_ajb = (const float*)d_in[8];
    const float* c1_nw  = (const float*)d_in[9];
    const float* c1_nb  = (const float*)d_in[10];
    const float* c1_ew  = (const float*)d_in[11];
    const float* c1_eb  = (const float*)d_in[12];

    const float* c2_sw  = (const float*)d_in[13];
    const float* c2_sb  = (const float*)d_in[14];
    const float* c2_aiw = (const float*)d_in[15];
    const float* c2_aib = (const float*)d_in[16];
    const float* c2_ajw = (const float*)d_in[17];
    const float* c2_ajb = (const float*)d_in[18];
    const float* c2_nw  = (const float*)d_in[19];
    const float* c2_nb  = (const float*)d_in[20];
    // d_in[21]/d_in[22] (c2_ew/c2_eb): layer-2 edge output is dead code
    const float* dw = (const float*)d_in[23];
    const float* db = (const float*)d_in[24];

    float* ws = (float*)d_ws;
    float* P1 = ws;                 // 12800
    float* Q1 = ws + 12800;         // 12800
    float* P2 = ws + 25600;         // 12800
    float* Q2 = ws + 38400;         // 12800
    float* x1 = ws + 51200;         // 96000
    float* x2 = ws + 147200;        // 96000
    float* e1 = ws + 243200;        // 160000

    float* out = (float*)d_out;

    // K1: layer-1 P/Q projection
    pq_kernel<<<NN, 256, 0, stream>>>(x, c1_sw, c1_sb, P1, Q1);

    // K2: layer-1 rcf + node model + layer-2 P/Q (all per-row, in-block)
    rcf_node<true, true><<<NN, 256, 0, stream>>>(
        P1, Q1, e0, a, c1_sw + 480 * CC,
        c1_aiw, c1_aib, c1_ajw, c1_ajb, c1_ew, c1_eb, e1,
        x, c1_nw, c1_nb, c2_sw, c2_sb, x1, P2, Q2);

    // K3: layer-2 rcf + node model (no e_out, no next PQ)
    rcf_node<false, false><<<NN, 256, 0, stream>>>(
        P2, Q2, e1, a, c2_sw + 480 * CC,
        c2_aiw, c2_aib, c2_ajw, c2_ajb, nullptr, nullptr, nullptr,
        x1, c2_nw, c2_nb, nullptr, nullptr, x2, nullptr, nullptr);

    // K4: final dense
    dense_kernel<<<dim3(NN / 4, 6), 256, 0, stream>>>(x2, dw, db, out);
}

// Round 7
// 69.214 us; speedup vs baseline: 5.9487x; 1.0499x over previous
//
#include <hip/hip_runtime.h>

#define NN 400
#define FF 240
#define CC 32
#define NIN 304   // F + 2C
#define LL 1440

// ---------------------------------------------------------------------------
// K1: P[i][c] = sb[c] + sum_f x[i][f]*sw[f*C+c] ; Q likewise with sw[F:2F].
// grid = N blocks, 256 threads.
// ---------------------------------------------------------------------------
__global__ __launch_bounds__(256) void pq_kernel(
    const float* __restrict__ x, const float* __restrict__ sw,
    const float* __restrict__ sb, float* __restrict__ P, float* __restrict__ Q) {
    const int i   = blockIdx.x;
    const int t   = threadIdx.x;
    const int c   = t & 31;
    const int isQ = (t >> 5) & 1;
    const int g   = t >> 6;            // 0..3, 60 f each
    const float* wb = sw + (isQ ? FF * CC : 0) + c;
    float acc = (!isQ && g == 0) ? sb[c] : 0.0f;
    const float* xr = x + i * FF;
    const int f0 = g * 60;
    #pragma unroll 4
    for (int f = f0; f < f0 + 60; ++f) acc += xr[f] * wb[f * CC];
    __shared__ float red[4][64];
    red[g][t & 63] = acc;
    __syncthreads();
    if (t < 64) {
        const float s = red[0][t] + red[1][t] + red[2][t] + red[3][t];
        if (t >= 32) Q[i * CC + (t & 31)] = s;
        else         P[i * CC + t] = s;
    }
}

// ---------------------------------------------------------------------------
// K2/K3: one 1024-thread block per row b (16 waves -> 6.25 waves/SIMD for
// latency hiding). rcf (row+col gates over all 400 k, 4 iterations of 128
// pairs), agg reduced in LDS (two stages), node model inline, then (layer 1)
// the next layer's P/Q projection. No cross-block traffic.
// pg = t>>3 pair-group in [0,128), l = t&7 channel quad.
// ---------------------------------------------------------------------------
template<bool WRITE_E, bool DO_PQ>
__global__ __launch_bounds__(1024) void rcf_node(
    const float* __restrict__ P, const float* __restrict__ Q,
    const float* __restrict__ e, const float* __restrict__ a,
    const float* __restrict__ sw_tail,   // sw + 480*CC : rows [w1 ; w2]
    const float* __restrict__ aiw, const float* __restrict__ aib,
    const float* __restrict__ ajw, const float* __restrict__ ajb,
    const float* __restrict__ ew, const float* __restrict__ eb,
    float* __restrict__ e_out,
    const float* __restrict__ xin, const float* __restrict__ nw,
    const float* __restrict__ nb,
    const float* __restrict__ sw2, const float* __restrict__ sb2,
    float* __restrict__ xout, float* __restrict__ Pout, float* __restrict__ Qout) {
    const int b  = blockIdx.x;
    const int t  = threadIdx.x;
    const int pg = t >> 3, l = t & 7, c0 = l * 4;

    __shared__ float smem[10272];
    float* red  = smem;          // 9216 = 256*36 (rcf reduce; later redn/red2)
    float* v    = smem + 9216;   // 304 (node input vector)
    float* xs   = smem + 9520;   // 240 (node output row)
    float* part = smem + 9760;   // 512 (stage-1 agg partials)
    float* redn = smem;          // 16*240 = 3840 (overlays red)
    float* red2 = smem;          // 16*64  = 1024 (overlays red)

    if (t < FF) v[t] = xin[b * FF + t];   // stage x-row early (hidden under rcf)

    // ---- rcf: both gate directions for row b over all k ----
    float w1v[4], w2v[4], wiv[4], wjv[4], wev[4], Pb[4], Qb[4];
    *(float4*)w1v = *(const float4*)(sw_tail + c0);
    *(float4*)w2v = *(const float4*)(sw_tail + CC + c0);
    *(float4*)wiv = *(const float4*)(aiw + c0);
    *(float4*)wjv = *(const float4*)(ajw + c0);
    if (WRITE_E) *(float4*)wev = *(const float4*)(ew + c0);
    *(float4*)Pb = *(const float4*)(P + b * CC + c0);
    *(float4*)Qb = *(const float4*)(Q + b * CC + c0);
    const float bi = aib[0], bj = ajb[0];
    const float be = WRITE_E ? eb[0] : 0.0f;

    float acc_i[4] = {0, 0, 0, 0}, acc_j[4] = {0, 0, 0, 0};
    #pragma unroll
    for (int it = 0; it < 4; ++it) {
        const int off = it * 128 + pg;
        const bool valid = off < NN;
        const int k = valid ? off : 0;
        float Qk[4], Pk[4];
        *(float4*)Qk = *(const float4*)(Q + k * CC + c0);
        *(float4*)Pk = *(const float4*)(P + k * CC + c0);
        const float e_f  = e[b * NN + k];
        const float e_r  = e[k * NN + b];
        const float a_bk = a[b * NN + k];
        const float a_kb = a[k * NN + b];
        float sr[4], sc[4];
        #pragma unroll
        for (int q = 0; q < 4; ++q) {
            sr[q] = fmaxf(Pb[q] + Qk[q] + e_f * w1v[q] + e_r * w2v[q], 0.0f) * a_bk;
            sc[q] = fmaxf(Pk[q] + Qb[q] + e_r * w1v[q] + e_f * w2v[q], 0.0f) * a_kb;
        }
        float d_i = sr[0] * wiv[0] + sr[1] * wiv[1] + sr[2] * wiv[2] + sr[3] * wiv[3];
        float d_j = sc[0] * wjv[0] + sc[1] * wjv[1] + sc[2] * wjv[2] + sc[3] * wjv[3];
        float d_e = WRITE_E ? (sr[0] * wev[0] + sr[1] * wev[1] + sr[2] * wev[2] + sr[3] * wev[3]) : 0.0f;
        #pragma unroll
        for (int m = 1; m < 8; m <<= 1) {
            d_i += __shfl_xor(d_i, m);
            d_j += __shfl_xor(d_j, m);
            if (WRITE_E) d_e += __shfl_xor(d_e, m);
        }
        const float gi = valid ? 1.0f / (1.0f + __expf(-(d_i + bi))) : 0.0f;
        const float gj = valid ? 1.0f / (1.0f + __expf(-(d_j + bj))) : 0.0f;
        #pragma unroll
        for (int q = 0; q < 4; ++q) {
            acc_i[q] += gi * sr[q];
            acc_j[q] += gj * sc[q];
        }
        if (WRITE_E && l == 0 && valid) e_out[b * NN + k] = d_e + be;
    }
    #pragma unroll
    for (int q = 0; q < 4; ++q) {
        red[pg * 36 + c0 + q]          = acc_i[q];
        red[(128 + pg) * 36 + c0 + q]  = acc_j[q];
    }
    __syncthreads();
    // stage-1: 512 threads each sum 16 pair-groups
    if (t < 512) {
        const int c = t & 31, sg = (t >> 5) & 7, which = t >> 8;
        float s = 0.0f;
        #pragma unroll
        for (int g2 = sg * 16; g2 < sg * 16 + 16; ++g2)
            s += red[(which * 128 + g2) * 36 + c];
        part[t] = s;
    }
    __syncthreads();
    // stage-2: agg_i (t<32) / agg_j (t in 32..63) land directly in v[240+t]
    if (t < 64) {
        const int which = t >> 5, c = t & 31;
        float s = 0.0f;
        #pragma unroll
        for (int sg = 0; sg < 8; ++sg) s += part[which * 256 + sg * 32 + c];
        v[FF + t] = s;
    }
    __syncthreads();

    // ---- node model: xout[b] = nb + v @ nw  (304 x 240), 960 threads ----
    {
        const int fg = t % 60, h = t / 60;   // h in [0,16), 19 k each
        if (t < 960) {
            const int f0 = fg * 4;
            float4 acc = make_float4(0.f, 0.f, 0.f, 0.f);
            const int k0 = h * 19;
            #pragma unroll
            for (int k = k0; k < k0 + 19; ++k) {
                const float vk = v[k];
                const float4 w = *(const float4*)(nw + k * FF + f0);
                acc.x += vk * w.x; acc.y += vk * w.y;
                acc.z += vk * w.z; acc.w += vk * w.w;
            }
            *(float4*)(redn + h * 240 + f0) = acc;
        }
    }
    __syncthreads();
    if (t < FF) {
        float r = nb[t];
        #pragma unroll
        for (int h = 0; h < 16; ++h) r += redn[h * 240 + t];
        xout[b * FF + t] = r;
        xs[t] = r;
    }
    if (DO_PQ) {
        __syncthreads();
        const int c = t & 31, isQ = (t >> 5) & 1, g = t >> 6;   // g in [0,16)
        const float* wb = sw2 + (isQ ? FF * CC : 0) + c;
        float acc = (!isQ && g == 0) ? sb2[c] : 0.0f;
        const int f0 = g * 15;
        #pragma unroll
        for (int f = f0; f < f0 + 15; ++f) acc += xs[f] * wb[f * CC];
        red2[g * 64 + (t & 63)] = acc;
        __syncthreads();
        if (t < 64) {
            float s = 0.0f;
            #pragma unroll
            for (int g2 = 0; g2 < 16; ++g2) s += red2[g2 * 64 + t];
            if (t >= 32) Qout[b * CC + (t & 31)] = s;
            else         Pout[b * CC + t] = s;
        }
    }
}

// ---------------------------------------------------------------------------
// K4: out[i][l] = db[l] + sum_f x2[i][f]*dw[f*L+l], 4 rows/block for dw reuse
// grid = (N/4, 6) blocks, 256 threads
// ---------------------------------------------------------------------------
__global__ __launch_bounds__(256) void dense_kernel(
    const float* __restrict__ x, const float* __restrict__ dw,
    const float* __restrict__ db, float* __restrict__ out) {
    const int i0 = blockIdx.x * 4;
    const int l  = blockIdx.y * 256 + threadIdx.x;
    __shared__ float xs[4][FF];
    for (int idx = threadIdx.x; idx < 4 * FF; idx += 256) {
        const int r = idx / FF, f = idx - r * FF;
        xs[r][f] = x[(i0 + r) * FF + f];
    }
    __syncthreads();
    if (l < LL) {
        float a0 = db[l], a1 = a0, a2 = a0, a3 = a0;
        #pragma unroll 4
        for (int f = 0; f < FF; ++f) {
            const float w = dw[f * LL + l];
            a0 += xs[0][f] * w;
            a1 += xs[1][f] * w;
            a2 += xs[2][f] * w;
            a3 += xs[3][f] * w;
        }
        out[(i0 + 0) * LL + l] = a0;
        out[(i0 + 1) * LL + l] = a1;
        out[(i0 + 2) * LL + l] = a2;
        out[(i0 + 3) * LL + l] = a3;
    }
}

extern "C" void kernel_launch(void* const* d_in, const int* in_sizes, int n_in,
                              void* d_out, int out_size, void* d_ws, size_t ws_size,
                              hipStream_t stream) {
    const float* x  = (const float*)d_in[0];
    const float* a  = (const float*)d_in[1];
    const float* e0 = (const float*)d_in[2];

    const float* c1_sw  = (const float*)d_in[3];
    const float* c1_sb  = (const float*)d_in[4];
    const float* c1_aiw = (const float*)d_in[5];
    const float* c1_aib = (const float*)d_in[6];
    const float* c1_ajw = (const float*)d_in[7];
    const float* c1_ajb = (const float*)d_in[8];
    const float* c1_nw  = (const float*)d_in[9];
    const float* c1_nb  = (const float*)d_in[10];
    const float* c1_ew  = (const float*)d_in[11];
    const float* c1_eb  = (const float*)d_in[12];

    const float* c2_sw  = (const float*)d_in[13];
    const float* c2_sb  = (const float*)d_in[14];
    const float* c2_aiw = (const float*)d_in[15];
    const float* c2_aib = (const float*)d_in[16];
    const float* c2_ajw = (const float*)d_in[17];
    const float* c2_ajb = (const float*)d_in[18];
    const float* c2_nw  = (const float*)d_in[19];
    const float* c2_nb  = (const float*)d_in[20];
    // d_in[21]/d_in[22] (c2_ew/c2_eb): layer-2 edge output is dead code
    const float* dw = (const float*)d_in[23];
    const float* db = (const float*)d_in[24];

    float* ws = (float*)d_ws;
    float* P1 = ws;                 // 12800
    float* Q1 = ws + 12800;         // 12800
    float* P2 = ws + 25600;         // 12800
    float* Q2 = ws + 38400;         // 12800
    float* x1 = ws + 51200;         // 96000
    float* x2 = ws + 147200;        // 96000
    float* e1 = ws + 243200;        // 160000

    float* out = (float*)d_out;

    // K1: layer-1 P/Q projection
    pq_kernel<<<NN, 256, 0, stream>>>(x, c1_sw, c1_sb, P1, Q1);

    // K2: layer-1 rcf + node model + layer-2 P/Q (all per-row, in-block)
    rcf_node<true, true><<<NN, 1024, 0, stream>>>(
        P1, Q1, e0, a, c1_sw + 480 * CC,
        c1_aiw, c1_aib, c1_ajw, c1_ajb, c1_ew, c1_eb, e1,
        x, c1_nw, c1_nb, c2_sw, c2_sb, x1, P2, Q2);

    // K3: layer-2 rcf + node model (no e_out, no next PQ)
    rcf_node<false, false><<<NN, 1024, 0, stream>>>(
        P2, Q2, e1, a, c2_sw + 480 * CC,
        c2_aiw, c2_aib, c2_ajw, c2_ajb, nullptr, nullptr, nullptr,
        x1, c2_nw, c2_nb, nullptr, nullptr, x2, nullptr, nullptr);

    // K4: final dense
    dense_kernel<<<dim3(NN / 4, 6), 256, 0, stream>>>(x2, dw, db, out);
}

// Round 8
// 62.423 us; speedup vs baseline: 6.5959x; 1.1088x over previous
//
#include <hip/hip_runtime.h>

#define NN 400
#define FF 240
#define CC 32
#define NIN 304   // F + 2C
#define LL 1440

// ---------------------------------------------------------------------------
// K1: P[i][c] = sb[c] + sum_f x[i][f]*sw[f*C+c] ; Q likewise with sw[F:2F].
// grid = N blocks, 256 threads.
// ---------------------------------------------------------------------------
__global__ __launch_bounds__(256) void pq_kernel(
    const float* __restrict__ x, const float* __restrict__ sw,
    const float* __restrict__ sb, float* __restrict__ P, float* __restrict__ Q) {
    const int i   = blockIdx.x;
    const int t   = threadIdx.x;
    const int c   = t & 31;
    const int isQ = (t >> 5) & 1;
    const int g   = t >> 6;            // 0..3, 60 f each
    const float* wb = sw + (isQ ? FF * CC : 0) + c;
    float acc = (!isQ && g == 0) ? sb[c] : 0.0f;
    const float* xr = x + i * FF;
    const int f0 = g * 60;
    #pragma unroll 4
    for (int f = f0; f < f0 + 60; ++f) acc += xr[f] * wb[f * CC];
    __shared__ float red[4][64];
    red[g][t & 63] = acc;
    __syncthreads();
    if (t < 64) {
        const float s = red[0][t] + red[1][t] + red[2][t] + red[3][t];
        if (t >= 32) Q[i * CC + (t & 31)] = s;
        else         P[i * CC + t] = s;
    }
}

// ---------------------------------------------------------------------------
// K2/K3: one 1024-thread block per row b. XCD-swizzled b so rows 0..49 share
// an XCD (column gather lines shared 8-way in that XCD's L2). rcf over all
// 400 k (4 iterations of 128 pairs, gathers hoisted for MLP), agg reduced in
// LDS, node model inline, then (layer 1) next layer's P/Q projection.
// pg = t>>3 pair-group in [0,128), l = t&7 channel quad.
// ---------------------------------------------------------------------------
template<bool WRITE_E, bool DO_PQ>
__global__ __launch_bounds__(1024) void rcf_node(
    const float* __restrict__ P, const float* __restrict__ Q,
    const float* __restrict__ e, const float* __restrict__ a,
    const float* __restrict__ sw_tail,   // sw + 480*CC : rows [w1 ; w2]
    const float* __restrict__ aiw, const float* __restrict__ aib,
    const float* __restrict__ ajw, const float* __restrict__ ajb,
    const float* __restrict__ ew, const float* __restrict__ eb,
    float* __restrict__ e_out,
    const float* __restrict__ xin, const float* __restrict__ nw,
    const float* __restrict__ nb,
    const float* __restrict__ sw2, const float* __restrict__ sb2,
    float* __restrict__ xout, float* __restrict__ Pout, float* __restrict__ Qout) {
    // XCD-aware swizzle: 400 = 8 XCDs * 50 rows, bijective
    const int bid = blockIdx.x;
    const int b   = (bid & 7) * 50 + (bid >> 3);
    const int t  = threadIdx.x;
    const int pg = t >> 3, l = t & 7, c0 = l * 4;

    __shared__ float smem[10272];
    float* red  = smem;          // 9216 = 256*36 (rcf reduce; later redn/red2)
    float* v    = smem + 9216;   // 304 (node input vector)
    float* xs   = smem + 9520;   // 240 (node output row)
    float* part = smem + 9760;   // 512 (stage-1 agg partials)
    float* redn = smem;          // 16*240 = 3840 (overlays red)
    float* red2 = smem;          // 16*64  = 1024 (overlays red)

    if (t < FF) v[t] = xin[b * FF + t];   // stage x-row early (hidden under rcf)

    // ---- hoisted gather/row loads: 16-deep MLP on the latency-bound lines ----
    float e_f4[4], e_r4[4], a_bk4[4], a_kb4[4];
    int kk[4];
    #pragma unroll
    for (int it = 0; it < 4; ++it) {
        const int off = it * 128 + pg;
        kk[it] = (off < NN) ? off : 0;
        e_f4[it]  = e[b * NN + kk[it]];
        e_r4[it]  = e[kk[it] * NN + b];
        a_bk4[it] = a[b * NN + kk[it]];
        a_kb4[it] = a[kk[it] * NN + b];
    }

    // ---- rcf: both gate directions for row b over all k ----
    float w1v[4], w2v[4], wiv[4], wjv[4], wev[4], Pb[4], Qb[4];
    *(float4*)w1v = *(const float4*)(sw_tail + c0);
    *(float4*)w2v = *(const float4*)(sw_tail + CC + c0);
    *(float4*)wiv = *(const float4*)(aiw + c0);
    *(float4*)wjv = *(const float4*)(ajw + c0);
    if (WRITE_E) *(float4*)wev = *(const float4*)(ew + c0);
    *(float4*)Pb = *(const float4*)(P + b * CC + c0);
    *(float4*)Qb = *(const float4*)(Q + b * CC + c0);
    const float bi = aib[0], bj = ajb[0];
    const float be = WRITE_E ? eb[0] : 0.0f;

    float acc_i[4] = {0, 0, 0, 0}, acc_j[4] = {0, 0, 0, 0};
    #pragma unroll
    for (int it = 0; it < 4; ++it) {
        const int off = it * 128 + pg;
        const bool valid = off < NN;
        const int k = kk[it];
        float Qk[4], Pk[4];
        *(float4*)Qk = *(const float4*)(Q + k * CC + c0);
        *(float4*)Pk = *(const float4*)(P + k * CC + c0);
        const float e_f = e_f4[it], e_r = e_r4[it];
        const float a_bk = a_bk4[it], a_kb = a_kb4[it];
        float sr[4], sc[4];
        #pragma unroll
        for (int q = 0; q < 4; ++q) {
            sr[q] = fmaxf(Pb[q] + Qk[q] + e_f * w1v[q] + e_r * w2v[q], 0.0f) * a_bk;
            sc[q] = fmaxf(Pk[q] + Qb[q] + e_r * w1v[q] + e_f * w2v[q], 0.0f) * a_kb;
        }
        float d_i = sr[0] * wiv[0] + sr[1] * wiv[1] + sr[2] * wiv[2] + sr[3] * wiv[3];
        float d_j = sc[0] * wjv[0] + sc[1] * wjv[1] + sc[2] * wjv[2] + sc[3] * wjv[3];
        float d_e = WRITE_E ? (sr[0] * wev[0] + sr[1] * wev[1] + sr[2] * wev[2] + sr[3] * wev[3]) : 0.0f;
        #pragma unroll
        for (int m = 1; m < 8; m <<= 1) {
            d_i += __shfl_xor(d_i, m);
            d_j += __shfl_xor(d_j, m);
            if (WRITE_E) d_e += __shfl_xor(d_e, m);
        }
        const float gi = valid ? __fdividef(1.0f, 1.0f + __expf(-(d_i + bi))) : 0.0f;
        const float gj = valid ? __fdividef(1.0f, 1.0f + __expf(-(d_j + bj))) : 0.0f;
        #pragma unroll
        for (int q = 0; q < 4; ++q) {
            acc_i[q] += gi * sr[q];
            acc_j[q] += gj * sc[q];
        }
        if (WRITE_E && l == 0 && valid) e_out[b * NN + k] = d_e + be;
    }
    #pragma unroll
    for (int q = 0; q < 4; ++q) {
        red[pg * 36 + c0 + q]          = acc_i[q];
        red[(128 + pg) * 36 + c0 + q]  = acc_j[q];
    }
    __syncthreads();
    // stage-1: 512 threads each sum 16 pair-groups
    if (t < 512) {
        const int c = t & 31, sg = (t >> 5) & 7, which = t >> 8;
        float s = 0.0f;
        #pragma unroll
        for (int g2 = sg * 16; g2 < sg * 16 + 16; ++g2)
            s += red[(which * 128 + g2) * 36 + c];
        part[t] = s;
    }
    __syncthreads();
    // stage-2: agg_i (t<32) / agg_j (t in 32..63) land directly in v[240+t]
    if (t < 64) {
        const int which = t >> 5, c = t & 31;
        float s = 0.0f;
        #pragma unroll
        for (int sg = 0; sg < 8; ++sg) s += part[which * 256 + sg * 32 + c];
        v[FF + t] = s;
    }
    __syncthreads();

    // ---- node model: xout[b] = nb + v @ nw  (304 x 240), 960 threads ----
    {
        const int fg = t % 60, h = t / 60;   // h in [0,16), 19 k each
        if (t < 960) {
            const int f0 = fg * 4;
            float4 acc = make_float4(0.f, 0.f, 0.f, 0.f);
            const int k0 = h * 19;
            #pragma unroll
            for (int k = k0; k < k0 + 19; ++k) {
                const float vk = v[k];
                const float4 w = *(const float4*)(nw + k * FF + f0);
                acc.x += vk * w.x; acc.y += vk * w.y;
                acc.z += vk * w.z; acc.w += vk * w.w;
            }
            *(float4*)(redn + h * 240 + f0) = acc;
        }
    }
    __syncthreads();
    if (t < FF) {
        float r = nb[t];
        #pragma unroll
        for (int h = 0; h < 16; ++h) r += redn[h * 240 + t];
        xout[b * FF + t] = r;
        xs[t] = r;
    }
    if (DO_PQ) {
        __syncthreads();
        const int c = t & 31, isQ = (t >> 5) & 1, g = t >> 6;   // g in [0,16)
        const float* wb = sw2 + (isQ ? FF * CC : 0) + c;
        float acc = (!isQ && g == 0) ? sb2[c] : 0.0f;
        const int f0 = g * 15;
        #pragma unroll
        for (int f = f0; f < f0 + 15; ++f) acc += xs[f] * wb[f * CC];
        red2[g * 64 + (t & 63)] = acc;
        __syncthreads();
        if (t < 64) {
            float s = 0.0f;
            #pragma unroll
            for (int g2 = 0; g2 < 16; ++g2) s += red2[g2 * 64 + t];
            if (t >= 32) Qout[b * CC + (t & 31)] = s;
            else         Pout[b * CC + t] = s;
        }
    }
}

// ---------------------------------------------------------------------------
// K4: out[i][l] = db[l] + sum_f x2[i][f]*dw[f*L+l], 8 rows/block for dw reuse
// grid = (N/8, 6) blocks, 256 threads
// ---------------------------------------------------------------------------
__global__ __launch_bounds__(256) void dense_kernel(
    const float* __restrict__ x, const float* __restrict__ dw,
    const float* __restrict__ db, float* __restrict__ out) {
    const int i0 = blockIdx.x * 8;
    const int l  = blockIdx.y * 256 + threadIdx.x;
    __shared__ float xs[8][FF];
    for (int idx = threadIdx.x; idx < 8 * FF; idx += 256) {
        const int r = idx / FF, f = idx - r * FF;
        xs[r][f] = x[(i0 + r) * FF + f];
    }
    __syncthreads();
    if (l < LL) {
        float a0 = db[l], a1 = a0, a2 = a0, a3 = a0;
        float a4 = a0, a5 = a0, a6 = a0, a7 = a0;
        #pragma unroll 4
        for (int f = 0; f < FF; ++f) {
            const float w = dw[f * LL + l];
            a0 += xs[0][f] * w;
            a1 += xs[1][f] * w;
            a2 += xs[2][f] * w;
            a3 += xs[3][f] * w;
            a4 += xs[4][f] * w;
            a5 += xs[5][f] * w;
            a6 += xs[6][f] * w;
            a7 += xs[7][f] * w;
        }
        out[(i0 + 0) * LL + l] = a0;
        out[(i0 + 1) * LL + l] = a1;
        out[(i0 + 2) * LL + l] = a2;
        out[(i0 + 3) * LL + l] = a3;
        out[(i0 + 4) * LL + l] = a4;
        out[(i0 + 5) * LL + l] = a5;
        out[(i0 + 6) * LL + l] = a6;
        out[(i0 + 7) * LL + l] = a7;
    }
}

extern "C" void kernel_launch(void* const* d_in, const int* in_sizes, int n_in,
                              void* d_out, int out_size, void* d_ws, size_t ws_size,
                              hipStream_t stream) {
    const float* x  = (const float*)d_in[0];
    const float* a  = (const float*)d_in[1];
    const float* e0 = (const float*)d_in[2];

    const float* c1_sw  = (const float*)d_in[3];
    const float* c1_sb  = (const float*)d_in[4];
    const float* c1_aiw = (const float*)d_in[5];
    const float* c1_aib = (const float*)d_in[6];
    const float* c1_ajw = (const float*)d_in[7];
    const float* c1_ajb = (const float*)d_in[8];
    const float* c1_nw  = (const float*)d_in[9];
    const float* c1_nb  = (const float*)d_in[10];
    const float* c1_ew  = (const float*)d_in[11];
    const float* c1_eb  = (const float*)d_in[12];

    const float* c2_sw  = (const float*)d_in[13];
    const float* c2_sb  = (const float*)d_in[14];
    const float* c2_aiw = (const float*)d_in[15];
    const float* c2_aib = (const float*)d_in[16];
    const float* c2_ajw = (const float*)d_in[17];
    const float* c2_ajb = (const float*)d_in[18];
    const float* c2_nw  = (const float*)d_in[19];
    const float* c2_nb  = (const float*)d_in[20];
    // d_in[21]/d_in[22] (c2_ew/c2_eb): layer-2 edge output is dead code
    const float* dw = (const float*)d_in[23];
    const float* db = (const float*)d_in[24];

    float* ws = (float*)d_ws;
    float* P1 = ws;                 // 12800
    float* Q1 = ws + 12800;         // 12800
    float* P2 = ws + 25600;         // 12800
    float* Q2 = ws + 38400;         // 12800
    float* x1 = ws + 51200;         // 96000
    float* x2 = ws + 147200;        // 96000
    float* e1 = ws + 243200;        // 160000

    float* out = (float*)d_out;

    // K1: layer-1 P/Q projection
    pq_kernel<<<NN, 256, 0, stream>>>(x, c1_sw, c1_sb, P1, Q1);

    // K2: layer-1 rcf + node model + layer-2 P/Q (all per-row, in-block)
    rcf_node<true, true><<<NN, 1024, 0, stream>>>(
        P1, Q1, e0, a, c1_sw + 480 * CC,
        c1_aiw, c1_aib, c1_ajw, c1_ajb, c1_ew, c1_eb, e1,
        x, c1_nw, c1_nb, c2_sw, c2_sb, x1, P2, Q2);

    // K3: layer-2 rcf + node model (no e_out, no next PQ)
    rcf_node<false, false><<<NN, 1024, 0, stream>>>(
        P2, Q2, e1, a, c2_sw + 480 * CC,
        c2_aiw, c2_aib, c2_ajw, c2_ajb, nullptr, nullptr, nullptr,
        x1, c2_nw, c2_nb, nullptr, nullptr, x2, nullptr, nullptr);

    // K4: final dense
    dense_kernel<<<dim3(NN / 8, 6), 256, 0, stream>>>(x2, dw, db, out);
}